// Round 1
// baseline (319.170 us; speedup 1.0000x reference)
//
#include <hip/hip_runtime.h>
#include <math.h>

#define NN   40000     // nodes
#define EE   640000    // edges
#define INF_ 128       // in feats
#define OUTF 64        // out feats (K=8 factors x d=8)

// ---------------- CSR construction ----------------

__global__ void hist_k(const int* __restrict__ src, int* __restrict__ counts) {
    int e = blockIdx.x * blockDim.x + threadIdx.x;
    if (e < EE) atomicAdd(&counts[src[e]], 1);
}

__global__ void scan1_k(const int* __restrict__ counts, int* __restrict__ excl,
                        int* __restrict__ bsum) {
    __shared__ int tmp[256];
    int i = blockIdx.x * 256 + threadIdx.x;
    int v = (i < NN) ? counts[i] : 0;
    tmp[threadIdx.x] = v;
    __syncthreads();
    for (int off = 1; off < 256; off <<= 1) {
        int t = (threadIdx.x >= off) ? tmp[threadIdx.x - off] : 0;
        __syncthreads();
        tmp[threadIdx.x] += t;
        __syncthreads();
    }
    if (i < NN) excl[i] = tmp[threadIdx.x] - v;          // exclusive within block
    if (threadIdx.x == 255) bsum[blockIdx.x] = tmp[255]; // block total
}

__global__ void scan2_k(int* __restrict__ bsum, int nb) {
    __shared__ int tmp[256];
    int v = (threadIdx.x < nb) ? bsum[threadIdx.x] : 0;
    tmp[threadIdx.x] = v;
    __syncthreads();
    for (int off = 1; off < 256; off <<= 1) {
        int t = (threadIdx.x >= off) ? tmp[threadIdx.x - off] : 0;
        __syncthreads();
        tmp[threadIdx.x] += t;
        __syncthreads();
    }
    if (threadIdx.x < nb) bsum[threadIdx.x] = tmp[threadIdx.x] - v; // exclusive in place
}

__global__ void scan3_k(const int* __restrict__ excl, const int* __restrict__ bsum,
                        int* __restrict__ row_start, int* __restrict__ fill) {
    int i = blockIdx.x * 256 + threadIdx.x;
    if (i < NN) {
        int r = excl[i] + bsum[blockIdx.x];
        row_start[i] = r;
        fill[i] = r;
    }
    if (i == 0) row_start[NN] = EE;
}

__global__ void scatter_k(const int* __restrict__ src, const int* __restrict__ dst,
                          int* __restrict__ fill, int* __restrict__ csr_dst) {
    int e = blockIdx.x * blockDim.x + threadIdx.x;
    if (e < EE) {
        int s = src[e];
        int p = atomicAdd(&fill[s], 1);
        csr_dst[p] = dst[e];
    }
}

// ---------------- h = l2norm(leakyrelu(x@W + b)) ----------------
// one wave per node; W staged in LDS (32 KB); lane l owns output col l.

__global__ __launch_bounds__(256) void gemm_norm_k(const float* __restrict__ x,
                                                   const float* __restrict__ w,
                                                   const float* __restrict__ bias,
                                                   float* __restrict__ hn) {
    __shared__ float wl[INF_ * OUTF];   // 32 KB
    __shared__ float xl[4][INF_];       // 2 KB, per-wave row stage
    for (int i = threadIdx.x; i < INF_ * OUTF; i += 256) wl[i] = w[i];
    __syncthreads();
    int wv = threadIdx.x >> 6;
    int l  = threadIdx.x & 63;
    float bv = bias[l];
    int wid = blockIdx.x * 4 + wv;
    int wstride = gridDim.x * 4;
    for (int n = wid; n < NN; n += wstride) {
        // wave-coherent LDS stage of this node's x row (no block barrier needed)
        xl[wv][l]      = x[(size_t)n * INF_ + l];
        xl[wv][64 + l] = x[(size_t)n * INF_ + 64 + l];
        float acc = bv;
#pragma unroll
        for (int i = 0; i < INF_; ++i)
            acc = fmaf(xl[wv][i], wl[i * OUTF + l], acc);
        acc = (acc > 0.f) ? acc : (0.01f * acc);   // leaky relu, slope 0.01
        float sq = acc * acc;                      // l2 norm over 8-lane factor group
        sq += __shfl_xor(sq, 1, 8);
        sq += __shfl_xor(sq, 2, 8);
        sq += __shfl_xor(sq, 4, 8);
        hn[(size_t)n * OUTF + l] = acc * rsqrtf(sq);
    }
}

// ---------------- one attention iteration ----------------
// one wave per node; lane l = k*8 + j. Online segment-softmax over the node's
// CSR edge range; gathers only from constant h_normed (hsrc). In-place-safe:
// each wave reads/writes only its own node's h_dst row.

__global__ __launch_bounds__(256) void attn_iter_k(const float* __restrict__ hsrc,
                                                   const float* __restrict__ hdst_in,
                                                   float* __restrict__ hdst_out,
                                                   const int* __restrict__ row_start,
                                                   const int* __restrict__ csr_dst) {
    int wv = threadIdx.x >> 6;
    int l  = threadIdx.x & 63;
    int n  = blockIdx.x * 4 + wv;
    if (n >= NN) return;

    float hd    = hdst_in[(size_t)n * OUTF + l];
    float hself = hsrc[(size_t)n * OUTF + l];   // h_normed row (residual term)
    int beg = row_start[n], end = row_start[n + 1];

    float m = -INFINITY, ssum = 0.f, acc = 0.f;

    // 1-deep prefetch of the gathered neighbor row
    int   dv_next = (beg < end) ? csr_dst[beg] : 0;
    float f_next  = (beg < end) ? hsrc[(size_t)dv_next * OUTF + l] : 0.f;

    for (int e = beg; e < end; ++e) {
        float f = f_next;
        if (e + 1 < end) {
            int dv = csr_dst[e + 1];
            f_next = hsrc[(size_t)dv * OUTF + l];
        }
        float p = hd * f;                  // dot over d=8 within 8-lane group
        p += __shfl_xor(p, 1, 8);
        p += __shfl_xor(p, 2, 8);
        p += __shfl_xor(p, 4, 8);
        // s = p / TAU, TAU = 1
        float nm = fmaxf(m, p);
        float sc = __expf(m - nm);         // first iter: exp(-inf) = 0
        float ex = __expf(p - nm);
        ssum = ssum * sc + ex;
        acc  = acc  * sc + f * ex;
        m = nm;
    }

    float attr = hself;
    if (ssum > 0.f) attr += acc / ssum;    // empty segment -> just residual
    float sq = attr * attr;
    sq += __shfl_xor(sq, 1, 8);
    sq += __shfl_xor(sq, 2, 8);
    sq += __shfl_xor(sq, 4, 8);
    hdst_out[(size_t)n * OUTF + l] = attr * rsqrtf(sq);
}

// ---------------- launch ----------------

extern "C" void kernel_launch(void* const* d_in, const int* in_sizes, int n_in,
                              void* d_out, int out_size, void* d_ws, size_t ws_size,
                              hipStream_t stream) {
    const float* x    = (const float*)d_in[0];
    const float* w    = (const float*)d_in[1];
    const float* bias = (const float*)d_in[2];
    const int*   ei   = (const int*)d_in[3];
    const int*   src  = ei;        // edge_index[0] : softmax segment node
    const int*   dst  = ei + EE;   // edge_index[1] : gathered neighbor
    float* out = (float*)d_out;

    char* ws = (char*)d_ws;
    size_t off = 0;
    float* hn        = (float*)(ws + off); off += (size_t)NN * OUTF * sizeof(float); // 10.24 MB
    int*   counts    = (int*)(ws + off);   off += (size_t)NN * sizeof(int);
    int*   excl      = (int*)(ws + off);   off += (size_t)NN * sizeof(int);
    int*   bsum      = (int*)(ws + off);   off += 256 * sizeof(int);
    int*   row_start = (int*)(ws + off);   off += (size_t)(NN + 1) * sizeof(int);
    int*   fill      = (int*)(ws + off);   off += (size_t)NN * sizeof(int);
    int*   csr_dst   = (int*)(ws + off);   off += (size_t)EE * sizeof(int);
    (void)ws_size; (void)in_sizes; (void)n_in; (void)out_size;

    const int nscan = (NN + 255) / 256;   // 157

    hipMemsetAsync(counts, 0, (size_t)NN * sizeof(int), stream);
    hist_k   <<<(EE + 255) / 256, 256, 0, stream>>>(src, counts);
    scan1_k  <<<nscan, 256, 0, stream>>>(counts, excl, bsum);
    scan2_k  <<<1, 256, 0, stream>>>(bsum, nscan);
    scan3_k  <<<nscan, 256, 0, stream>>>(excl, bsum, row_start, fill);
    scatter_k<<<(EE + 255) / 256, 256, 0, stream>>>(src, dst, fill, csr_dst);

    gemm_norm_k<<<2048, 256, 0, stream>>>(x, w, bias, hn);

    const int ngrid = (NN + 3) / 4;       // 4 waves (nodes) per block
    attn_iter_k<<<ngrid, 256, 0, stream>>>(hn, hn,  out, row_start, csr_dst);
    attn_iter_k<<<ngrid, 256, 0, stream>>>(hn, out, out, row_start, csr_dst);
    attn_iter_k<<<ngrid, 256, 0, stream>>>(hn, out, out, row_start, csr_dst);
}

// Round 2
// 170.860 us; speedup vs baseline: 1.8680x; 1.8680x over previous
//
#include <hip/hip_runtime.h>
#include <math.h>

#define NN   40000     // nodes
#define EE   640000    // edges
#define INF_ 128       // in feats
#define OUTF 64        // out feats (K=8 factors x d=8)

// ---------------- CSR construction ----------------

__global__ void hist_k(const int* __restrict__ src, int* __restrict__ counts) {
    int e = blockIdx.x * blockDim.x + threadIdx.x;
    if (e < EE) atomicAdd(&counts[src[e]], 1);
}

__global__ void scan1_k(const int* __restrict__ counts, int* __restrict__ excl,
                        int* __restrict__ bsum) {
    __shared__ int tmp[256];
    int i = blockIdx.x * 256 + threadIdx.x;
    int v = (i < NN) ? counts[i] : 0;
    tmp[threadIdx.x] = v;
    __syncthreads();
    for (int off = 1; off < 256; off <<= 1) {
        int t = (threadIdx.x >= off) ? tmp[threadIdx.x - off] : 0;
        __syncthreads();
        tmp[threadIdx.x] += t;
        __syncthreads();
    }
    if (i < NN) excl[i] = tmp[threadIdx.x] - v;          // exclusive within block
    if (threadIdx.x == 255) bsum[blockIdx.x] = tmp[255]; // block total
}

__global__ void scan2_k(int* __restrict__ bsum, int nb) {
    __shared__ int tmp[256];
    int v = (threadIdx.x < nb) ? bsum[threadIdx.x] : 0;
    tmp[threadIdx.x] = v;
    __syncthreads();
    for (int off = 1; off < 256; off <<= 1) {
        int t = (threadIdx.x >= off) ? tmp[threadIdx.x - off] : 0;
        __syncthreads();
        tmp[threadIdx.x] += t;
        __syncthreads();
    }
    if (threadIdx.x < nb) bsum[threadIdx.x] = tmp[threadIdx.x] - v; // exclusive in place
}

__global__ void scan3_k(const int* __restrict__ excl, const int* __restrict__ bsum,
                        int* __restrict__ row_start, int* __restrict__ fill) {
    int i = blockIdx.x * 256 + threadIdx.x;
    if (i < NN) {
        int r = excl[i] + bsum[blockIdx.x];
        row_start[i] = r;
        fill[i] = r;
    }
    if (i == 0) row_start[NN] = EE;
}

__global__ void scatter_k(const int* __restrict__ src, const int* __restrict__ dst,
                          int* __restrict__ fill, int* __restrict__ csr_dst) {
    int e = blockIdx.x * blockDim.x + threadIdx.x;
    if (e < EE) {
        int s = src[e];
        int p = atomicAdd(&fill[s], 1);
        csr_dst[p] = dst[e];
    }
}

// ---------------- h = l2norm(leakyrelu(x@W + b)) ----------------
// 4 nodes per wave: lane = (q=node slot)<<4 | (r=col quad). W staged in LDS,
// each W float4 row-chunk multicast across the 4 quarters.

__global__ __launch_bounds__(256) void gemm_norm_k(const float* __restrict__ x,
                                                   const float* __restrict__ w,
                                                   const float* __restrict__ bias,
                                                   float* __restrict__ hn) {
    __shared__ float wl[INF_ * OUTF];     // 32 KB, [i][c]
    __shared__ float xl[4][4 * 132];      // 4 waves x 4 rows x (128 + 4 pad)
    for (int i = threadIdx.x; i < INF_ * OUTF; i += 256) wl[i] = w[i];

    int wv = threadIdx.x >> 6;
    int l  = threadIdx.x & 63;
    int q  = l >> 4;          // node slot within wave
    int r  = l & 15;          // col quad: cols 4r..4r+3
    float4 bv = ((const float4*)bias)[r];

    int n0 = (blockIdx.x * 4 + wv) * 4;   // 2500 blocks x 4 waves x 4 nodes = 40000
    // stage 4 x-rows (512 floats) into padded LDS rows
    {
        const float4* xs = (const float4*)(x + (size_t)n0 * INF_);
        float4 a = xs[l];
        float4 b = xs[l + 64];
        int ra = l >> 5, ca = (l & 31) * 4;          // float4 l -> row, col
        int rb = (l + 64) >> 5, cb = ((l + 64) & 31) * 4;
        *(float4*)&xl[wv][ra * 132 + ca] = a;
        *(float4*)&xl[wv][rb * 132 + cb] = b;
    }
    __syncthreads();   // covers wl too; all 256 threads reach it

    float4 acc = bv;
    const float* xrow = &xl[wv][q * 132];
#pragma unroll 4
    for (int i = 0; i < INF_; ++i) {
        float xv = xrow[i];
        float4 w4 = ((const float4*)wl)[i * 16 + r];
        acc.x = fmaf(xv, w4.x, acc.x);
        acc.y = fmaf(xv, w4.y, acc.y);
        acc.z = fmaf(xv, w4.z, acc.z);
        acc.w = fmaf(xv, w4.w, acc.w);
    }
    acc.x = acc.x > 0.f ? acc.x : 0.01f * acc.x;
    acc.y = acc.y > 0.f ? acc.y : 0.01f * acc.y;
    acc.z = acc.z > 0.f ? acc.z : 0.01f * acc.z;
    acc.w = acc.w > 0.f ? acc.w : 0.01f * acc.w;
    float sq = acc.x*acc.x + acc.y*acc.y + acc.z*acc.z + acc.w*acc.w;
    sq += __shfl_xor(sq, 1);              // pair lanes within factor
    float inv = rsqrtf(sq);
    float4 o = make_float4(acc.x*inv, acc.y*inv, acc.z*inv, acc.w*inv);
    ((float4*)hn)[(size_t)(n0 + q) * 16 + r] = o;
}

// ---------------- one attention iteration ----------------
// one wave per node; 4 edges per loop iteration. lane = q<<4 | r:
//   q = edge slot (0..3), r = element quad (elements 4r..4r+3, factor k = r>>1).
// Softmax without max-subtraction: s = <u,v> in [-1,1] (unit vectors, tau=1),
// so exp(s) is always safe -> no fmax/rescale chain, order-free accumulation.

__global__ __launch_bounds__(256) void attn_iter_k(const float* __restrict__ hsrc,
                                                   const float* __restrict__ hdst_in,
                                                   float* __restrict__ hdst_out,
                                                   const int* __restrict__ row_start,
                                                   const int* __restrict__ csr_dst) {
    int wv = threadIdx.x >> 6;
    int l  = threadIdx.x & 63;
    int n  = blockIdx.x * 4 + wv;
    if (n >= NN) return;
    int q = l >> 4, r = l & 15;

    const float4* hsrc4 = (const float4*)hsrc;
    float4 hd    = ((const float4*)hdst_in)[(size_t)n * 16 + r];
    float4 hself = hsrc4[(size_t)n * 16 + r];

    int beg = row_start[n], end = row_start[n + 1];

    float  ssum = 0.f;
    float4 acc  = make_float4(0.f, 0.f, 0.f, 0.f);

    // 1-deep software pipeline over 4-edge groups
    int  e   = beg + q;
    bool okn = e < end;
    int  dvn = okn ? csr_dst[e] : 0;
    float4 fn = hsrc4[(size_t)dvn * 16 + r];

    for (int g = beg; g < end; g += 4) {
        bool   ok = okn;
        float4 f  = fn;
        e += 4;
        okn = e < end;
        int dv2 = okn ? csr_dst[e] : 0;
        fn = hsrc4[(size_t)dv2 * 16 + r];          // prefetch next group

        float p = f.x*hd.x + f.y*hd.y + f.z*hd.z + f.w*hd.w;
        p += __shfl_xor(p, 1);                     // full 8-dot for factor r>>1
        float ex = ok ? __expf(p) : 0.f;
        ssum += ex;
        acc.x = fmaf(f.x, ex, acc.x);
        acc.y = fmaf(f.y, ex, acc.y);
        acc.z = fmaf(f.z, ex, acc.z);
        acc.w = fmaf(f.w, ex, acc.w);
    }

    // combine the 4 edge-slot quarters (disjoint edge sets)
    ssum += __shfl_xor(ssum, 16);
    ssum += __shfl_xor(ssum, 32);
    acc.x += __shfl_xor(acc.x, 16); acc.x += __shfl_xor(acc.x, 32);
    acc.y += __shfl_xor(acc.y, 16); acc.y += __shfl_xor(acc.y, 32);
    acc.z += __shfl_xor(acc.z, 16); acc.z += __shfl_xor(acc.z, 32);
    acc.w += __shfl_xor(acc.w, 16); acc.w += __shfl_xor(acc.w, 32);

    float rs = (ssum > 0.f) ? 1.f / ssum : 0.f;    // empty segment -> residual only
    float4 attr = make_float4(fmaf(acc.x, rs, hself.x),
                              fmaf(acc.y, rs, hself.y),
                              fmaf(acc.z, rs, hself.z),
                              fmaf(acc.w, rs, hself.w));
    float sq = attr.x*attr.x + attr.y*attr.y + attr.z*attr.z + attr.w*attr.w;
    sq += __shfl_xor(sq, 1);
    float inv = rsqrtf(sq);
    attr.x *= inv; attr.y *= inv; attr.z *= inv; attr.w *= inv;
    if (l < 16)
        ((float4*)hdst_out)[(size_t)n * 16 + r] = attr;
}

// ---------------- launch ----------------

extern "C" void kernel_launch(void* const* d_in, const int* in_sizes, int n_in,
                              void* d_out, int out_size, void* d_ws, size_t ws_size,
                              hipStream_t stream) {
    const float* x    = (const float*)d_in[0];
    const float* w    = (const float*)d_in[1];
    const float* bias = (const float*)d_in[2];
    const int*   ei   = (const int*)d_in[3];
    const int*   src  = ei;        // edge_index[0] : softmax segment node
    const int*   dst  = ei + EE;   // edge_index[1] : gathered neighbor
    float* out = (float*)d_out;

    char* ws = (char*)d_ws;
    size_t off = 0;
    float* hn        = (float*)(ws + off); off += (size_t)NN * OUTF * sizeof(float); // 10.24 MB
    int*   counts    = (int*)(ws + off);   off += (size_t)NN * sizeof(int);
    int*   excl      = (int*)(ws + off);   off += (size_t)NN * sizeof(int);
    int*   bsum      = (int*)(ws + off);   off += 256 * sizeof(int);
    int*   row_start = (int*)(ws + off);   off += (size_t)(NN + 1) * sizeof(int);
    int*   fill      = (int*)(ws + off);   off += (size_t)NN * sizeof(int);
    int*   csr_dst   = (int*)(ws + off);   off += (size_t)EE * sizeof(int);
    (void)ws_size; (void)in_sizes; (void)n_in; (void)out_size;

    const int nscan = (NN + 255) / 256;   // 157

    hipMemsetAsync(counts, 0, (size_t)NN * sizeof(int), stream);
    hist_k   <<<(EE + 255) / 256, 256, 0, stream>>>(src, counts);
    scan1_k  <<<nscan, 256, 0, stream>>>(counts, excl, bsum);
    scan2_k  <<<1, 256, 0, stream>>>(bsum, nscan);
    scan3_k  <<<nscan, 256, 0, stream>>>(excl, bsum, row_start, fill);
    scatter_k<<<(EE + 255) / 256, 256, 0, stream>>>(src, dst, fill, csr_dst);

    gemm_norm_k<<<NN / 16, 256, 0, stream>>>(x, w, bias, hn);   // 2500 blocks

    const int ngrid = (NN + 3) / 4;       // one wave (node) x 4 per block
    attn_iter_k<<<ngrid, 256, 0, stream>>>(hn, hn,  out, row_start, csr_dst);
    attn_iter_k<<<ngrid, 256, 0, stream>>>(hn, out, out, row_start, csr_dst);
    attn_iter_k<<<ngrid, 256, 0, stream>>>(hn, out, out, row_start, csr_dst);
}

// Round 3
// 167.665 us; speedup vs baseline: 1.9036x; 1.0191x over previous
//
#include <hip/hip_runtime.h>
#include <math.h>

#define NN   40000     // nodes
#define EE   640000    // edges
#define INF_ 128       // in feats
#define OUTF 64        // out feats (K=8 factors x d=8)

// ---------------- CSR construction ----------------

__global__ void zero_k(int* __restrict__ c) {
    int i = blockIdx.x * 256 + threadIdx.x;
    if (i < NN) c[i] = 0;
}

__global__ void hist_k(const int4* __restrict__ src4, int* __restrict__ counts) {
    int t = blockIdx.x * blockDim.x + threadIdx.x;
    if (t < EE / 4) {
        int4 s = src4[t];
        atomicAdd(&counts[s.x], 1);
        atomicAdd(&counts[s.y], 1);
        atomicAdd(&counts[s.z], 1);
        atomicAdd(&counts[s.w], 1);
    }
}

__global__ void scan1_k(const int* __restrict__ counts, int* __restrict__ excl,
                        int* __restrict__ bsum) {
    __shared__ int tmp[256];
    int i = blockIdx.x * 256 + threadIdx.x;
    int v = (i < NN) ? counts[i] : 0;
    tmp[threadIdx.x] = v;
    __syncthreads();
    for (int off = 1; off < 256; off <<= 1) {
        int t = (threadIdx.x >= off) ? tmp[threadIdx.x - off] : 0;
        __syncthreads();
        tmp[threadIdx.x] += t;
        __syncthreads();
    }
    if (i < NN) excl[i] = tmp[threadIdx.x] - v;          // exclusive within block
    if (threadIdx.x == 255) bsum[blockIdx.x] = tmp[255]; // block total
}

__global__ void scan2_k(int* __restrict__ bsum, int nb) {
    __shared__ int tmp[256];
    int v = (threadIdx.x < nb) ? bsum[threadIdx.x] : 0;
    tmp[threadIdx.x] = v;
    __syncthreads();
    for (int off = 1; off < 256; off <<= 1) {
        int t = (threadIdx.x >= off) ? tmp[threadIdx.x - off] : 0;
        __syncthreads();
        tmp[threadIdx.x] += t;
        __syncthreads();
    }
    if (threadIdx.x < nb) bsum[threadIdx.x] = tmp[threadIdx.x] - v; // exclusive in place
}

__global__ void scan3_k(const int* __restrict__ excl, const int* __restrict__ bsum,
                        int* __restrict__ row_start, int* __restrict__ fill) {
    int i = blockIdx.x * 256 + threadIdx.x;
    if (i < NN) {
        int r = excl[i] + bsum[blockIdx.x];
        row_start[i] = r;
        fill[i] = r;
    }
    if (i == 0) row_start[NN] = EE;
}

__global__ void scatter_k(const int4* __restrict__ src4, const int4* __restrict__ dst4,
                          int* __restrict__ fill, int* __restrict__ csr_dst) {
    int t = blockIdx.x * blockDim.x + threadIdx.x;
    if (t < EE / 4) {
        int4 s = src4[t];
        int4 d = dst4[t];
        csr_dst[atomicAdd(&fill[s.x], 1)] = d.x;
        csr_dst[atomicAdd(&fill[s.y], 1)] = d.y;
        csr_dst[atomicAdd(&fill[s.z], 1)] = d.z;
        csr_dst[atomicAdd(&fill[s.w], 1)] = d.w;
    }
}

// ---------------- h = l2norm(leakyrelu(x@W + b)) ----------------
// 4 nodes per wave: lane = (q=node slot)<<4 | (r=col quad). W staged in LDS.
// Writes both f32 table (residual/h_dst reads) and bf16 table (edge gathers).

__device__ __forceinline__ unsigned short f2bf(float f) {
    unsigned u = __float_as_uint(f);
    return (unsigned short)((u + 0x7fffu + ((u >> 16) & 1u)) >> 16);  // RNE
}

__global__ __launch_bounds__(256) void gemm_norm_k(const float* __restrict__ x,
                                                   const float* __restrict__ w,
                                                   const float* __restrict__ bias,
                                                   float* __restrict__ hn,
                                                   unsigned short* __restrict__ hn16) {
    __shared__ float wl[INF_ * OUTF];     // 32 KB, [i][c]
    __shared__ float xl[4][4 * 132];      // 4 waves x 4 rows x (128 + 4 pad)
    for (int i = threadIdx.x; i < INF_ * OUTF; i += 256) wl[i] = w[i];

    int wv = threadIdx.x >> 6;
    int l  = threadIdx.x & 63;
    int q  = l >> 4;          // node slot within wave
    int r  = l & 15;          // col quad: cols 4r..4r+3
    float4 bv = ((const float4*)bias)[r];

    int n0 = (blockIdx.x * 4 + wv) * 4;   // 2500 blocks x 4 waves x 4 nodes = 40000
    {
        const float4* xs = (const float4*)(x + (size_t)n0 * INF_);
        float4 a = xs[l];
        float4 b = xs[l + 64];
        int ra = l >> 5, ca = (l & 31) * 4;
        int rb = (l + 64) >> 5, cb = ((l + 64) & 31) * 4;
        *(float4*)&xl[wv][ra * 132 + ca] = a;
        *(float4*)&xl[wv][rb * 132 + cb] = b;
    }
    __syncthreads();   // covers wl too

    float4 acc = bv;
    const float* xrow = &xl[wv][q * 132];
#pragma unroll 4
    for (int i = 0; i < INF_; ++i) {
        float xv = xrow[i];
        float4 w4 = ((const float4*)wl)[i * 16 + r];
        acc.x = fmaf(xv, w4.x, acc.x);
        acc.y = fmaf(xv, w4.y, acc.y);
        acc.z = fmaf(xv, w4.z, acc.z);
        acc.w = fmaf(xv, w4.w, acc.w);
    }
    acc.x = acc.x > 0.f ? acc.x : 0.01f * acc.x;
    acc.y = acc.y > 0.f ? acc.y : 0.01f * acc.y;
    acc.z = acc.z > 0.f ? acc.z : 0.01f * acc.z;
    acc.w = acc.w > 0.f ? acc.w : 0.01f * acc.w;
    float sq = acc.x*acc.x + acc.y*acc.y + acc.z*acc.z + acc.w*acc.w;
    sq += __shfl_xor(sq, 1);              // pair lanes within factor
    float inv = rsqrtf(sq);
    float4 o = make_float4(acc.x*inv, acc.y*inv, acc.z*inv, acc.w*inv);
    ((float4*)hn)[(size_t)(n0 + q) * 16 + r] = o;
    ushort4 o16;
    o16.x = f2bf(o.x); o16.y = f2bf(o.y); o16.z = f2bf(o.z); o16.w = f2bf(o.w);
    ((ushort4*)hn16)[(size_t)(n0 + q) * 16 + r] = o16;
}

// ---------------- one attention iteration ----------------
// one wave per node, 8 edges per loop iteration. lane = q<<3 | r:
//   q = edge slot (0..7), r = factor (0..7); lane holds the factor's full 8 dims.
// One uint4 (16 B) bf16 gather per lane = 8 full neighbor rows per instruction.
// Dot is fully in-lane (no shuffle per edge); exp computed once per (edge,factor).
// No max-subtraction: s = <u,v> in [-1,1] for unit vectors, exp always safe.

__global__ __launch_bounds__(256) void attn_iter_k(const uint4* __restrict__ hg,   // bf16 table
                                                   const float* __restrict__ hnf,  // f32 table
                                                   const float* __restrict__ hdst_in,
                                                   float* __restrict__ hdst_out,
                                                   const int* __restrict__ row_start,
                                                   const int* __restrict__ csr_dst) {
    int wv = threadIdx.x >> 6;
    int l  = threadIdx.x & 63;
    int n  = blockIdx.x * 4 + wv;
    if (n >= NN) return;
    int q = l >> 3, r = l & 7;

    const float4* hd4 = (const float4*)(hdst_in + (size_t)n * OUTF + r * 8);
    float4 hda = hd4[0], hdb = hd4[1];

    int beg = row_start[n], end = row_start[n + 1];

    float ssum = 0.f;
    float a0=0.f,a1=0.f,a2=0.f,a3=0.f,a4=0.f,a5=0.f,a6=0.f,a7=0.f;

    int  e   = beg + q;
    bool okn = e < end;
    int  dvn = okn ? csr_dst[e] : 0;
    uint4 fn = hg[(size_t)dvn * 8 + r];

    for (int g = beg; g < end; g += 8) {
        bool  ok = okn;
        uint4 f  = fn;
        e += 8;
        okn = e < end;
        int dv = okn ? csr_dst[e] : 0;
        fn = hg[(size_t)dv * 8 + r];                 // prefetch next group

        float f0 = __uint_as_float(f.x << 16), f1 = __uint_as_float(f.x & 0xffff0000u);
        float f2 = __uint_as_float(f.y << 16), f3 = __uint_as_float(f.y & 0xffff0000u);
        float f4 = __uint_as_float(f.z << 16), f5 = __uint_as_float(f.z & 0xffff0000u);
        float f6 = __uint_as_float(f.w << 16), f7 = __uint_as_float(f.w & 0xffff0000u);

        float p = f0*hda.x + f1*hda.y + f2*hda.z + f3*hda.w
                + f4*hdb.x + f5*hdb.y + f6*hdb.z + f7*hdb.w;
        float ex = ok ? __expf(p) : 0.f;
        ssum += ex;
        a0 = fmaf(f0, ex, a0); a1 = fmaf(f1, ex, a1);
        a2 = fmaf(f2, ex, a2); a3 = fmaf(f3, ex, a3);
        a4 = fmaf(f4, ex, a4); a5 = fmaf(f5, ex, a5);
        a6 = fmaf(f6, ex, a6); a7 = fmaf(f7, ex, a7);
    }

    // combine the 8 edge-slot groups (disjoint edge sets) across q
#pragma unroll
    for (int m = 8; m < 64; m <<= 1) {
        ssum += __shfl_xor(ssum, m);
        a0 += __shfl_xor(a0, m); a1 += __shfl_xor(a1, m);
        a2 += __shfl_xor(a2, m); a3 += __shfl_xor(a3, m);
        a4 += __shfl_xor(a4, m); a5 += __shfl_xor(a5, m);
        a6 += __shfl_xor(a6, m); a7 += __shfl_xor(a7, m);
    }

    float rs = (ssum > 0.f) ? 1.f / ssum : 0.f;      // empty segment -> residual only
    const float4* hs4 = (const float4*)(hnf + (size_t)n * OUTF + r * 8);
    float4 hsa = hs4[0], hsb = hs4[1];
    float t0 = fmaf(a0, rs, hsa.x), t1 = fmaf(a1, rs, hsa.y);
    float t2 = fmaf(a2, rs, hsa.z), t3 = fmaf(a3, rs, hsa.w);
    float t4 = fmaf(a4, rs, hsb.x), t5 = fmaf(a5, rs, hsb.y);
    float t6 = fmaf(a6, rs, hsb.z), t7 = fmaf(a7, rs, hsb.w);
    float sq = t0*t0+t1*t1+t2*t2+t3*t3+t4*t4+t5*t5+t6*t6+t7*t7;
    float inv = rsqrtf(sq);
    if (q == 0) {
        float4* o4 = (float4*)(hdst_out + (size_t)n * OUTF + r * 8);
        o4[0] = make_float4(t0*inv, t1*inv, t2*inv, t3*inv);
        o4[1] = make_float4(t4*inv, t5*inv, t6*inv, t7*inv);
    }
}

// ---------------- launch ----------------

extern "C" void kernel_launch(void* const* d_in, const int* in_sizes, int n_in,
                              void* d_out, int out_size, void* d_ws, size_t ws_size,
                              hipStream_t stream) {
    const float* x    = (const float*)d_in[0];
    const float* w    = (const float*)d_in[1];
    const float* bias = (const float*)d_in[2];
    const int*   ei   = (const int*)d_in[3];
    const int*   src  = ei;        // edge_index[0] : softmax segment node
    const int*   dst  = ei + EE;   // edge_index[1] : gathered neighbor
    float* out = (float*)d_out;

    char* ws = (char*)d_ws;
    size_t off = 0;
    float*          hn   = (float*)(ws + off);          off += (size_t)NN * OUTF * sizeof(float);  // 10.24 MB
    float*          hdst = (float*)(ws + off);          off += (size_t)NN * OUTF * sizeof(float);  // 10.24 MB
    unsigned short* hn16 = (unsigned short*)(ws + off); off += (size_t)NN * OUTF * sizeof(short);  // 5.12 MB
    int* counts    = (int*)(ws + off); off += (size_t)NN * sizeof(int);
    int* excl      = (int*)(ws + off); off += (size_t)NN * sizeof(int);
    int* bsum      = (int*)(ws + off); off += 256 * sizeof(int);
    int* row_start = (int*)(ws + off); off += (size_t)(NN + 1) * sizeof(int);
    int* fill      = (int*)(ws + off); off += (size_t)NN * sizeof(int);
    int* csr_dst   = (int*)(ws + off); off += (size_t)EE * sizeof(int);
    (void)ws_size; (void)in_sizes; (void)n_in; (void)out_size;

    const int nscan = (NN + 255) / 256;   // 157

    zero_k   <<<nscan, 256, 0, stream>>>(counts);
    hist_k   <<<(EE/4 + 255) / 256, 256, 0, stream>>>((const int4*)src, counts);
    scan1_k  <<<nscan, 256, 0, stream>>>(counts, excl, bsum);
    scan2_k  <<<1, 256, 0, stream>>>(bsum, nscan);
    scan3_k  <<<nscan, 256, 0, stream>>>(excl, bsum, row_start, fill);
    scatter_k<<<(EE/4 + 255) / 256, 256, 0, stream>>>((const int4*)src, (const int4*)dst,
                                                      fill, csr_dst);

    gemm_norm_k<<<NN / 16, 256, 0, stream>>>(x, w, bias, hn, hn16);

    const int ngrid = (NN + 3) / 4;       // 4 waves (nodes) per block
    attn_iter_k<<<ngrid, 256, 0, stream>>>((const uint4*)hn16, hn, hn,   hdst, row_start, csr_dst);
    attn_iter_k<<<ngrid, 256, 0, stream>>>((const uint4*)hn16, hn, hdst, hdst, row_start, csr_dst);
    attn_iter_k<<<ngrid, 256, 0, stream>>>((const uint4*)hn16, hn, hdst, out,  row_start, csr_dst);
}

// Round 4
// 113.083 us; speedup vs baseline: 2.8224x; 1.4827x over previous
//
#include <hip/hip_runtime.h>
#include <math.h>

#define NN   40000     // nodes
#define EE   640000    // edges
#define INF_ 128       // in feats
#define OUTF 64        // out feats (K=8 factors x d=8)

// ---------------- CSR construction ----------------

__global__ void zero_k(int* __restrict__ c) {
    int i = blockIdx.x * 256 + threadIdx.x;
    if (i < NN) c[i] = 0;
}

// histogram; atomicAdd return value = within-segment rank (stored for atomic-free place)
__global__ void hist_k(const int4* __restrict__ src4, int* __restrict__ counts,
                       int4* __restrict__ rank4) {
    int t = blockIdx.x * blockDim.x + threadIdx.x;
    if (t < EE / 4) {
        int4 s = src4[t];
        int4 r;
        r.x = atomicAdd(&counts[s.x], 1);
        r.y = atomicAdd(&counts[s.y], 1);
        r.z = atomicAdd(&counts[s.z], 1);
        r.w = atomicAdd(&counts[s.w], 1);
        rank4[t] = r;
    }
}

__global__ void scan1_k(const int* __restrict__ counts, int* __restrict__ excl,
                        int* __restrict__ bsum) {
    __shared__ int tmp[256];
    int i = blockIdx.x * 256 + threadIdx.x;
    int v = (i < NN) ? counts[i] : 0;
    tmp[threadIdx.x] = v;
    __syncthreads();
    for (int off = 1; off < 256; off <<= 1) {
        int t = (threadIdx.x >= off) ? tmp[threadIdx.x - off] : 0;
        __syncthreads();
        tmp[threadIdx.x] += t;
        __syncthreads();
    }
    if (i < NN) excl[i] = tmp[threadIdx.x] - v;          // exclusive within block
    if (threadIdx.x == 255) bsum[blockIdx.x] = tmp[255]; // block total
}

__global__ void scan2_k(int* __restrict__ bsum, int nb) {
    __shared__ int tmp[256];
    int v = (threadIdx.x < nb) ? bsum[threadIdx.x] : 0;
    tmp[threadIdx.x] = v;
    __syncthreads();
    for (int off = 1; off < 256; off <<= 1) {
        int t = (threadIdx.x >= off) ? tmp[threadIdx.x - off] : 0;
        __syncthreads();
        tmp[threadIdx.x] += t;
        __syncthreads();
    }
    if (threadIdx.x < nb) bsum[threadIdx.x] = tmp[threadIdx.x] - v; // exclusive in place
}

__global__ void scan3_k(const int* __restrict__ excl, const int* __restrict__ bsum,
                        int* __restrict__ row_start) {
    int i = blockIdx.x * 256 + threadIdx.x;
    if (i < NN) row_start[i] = excl[i] + bsum[blockIdx.x];
    if (i == 0) row_start[NN] = EE;
}

// atomic-free placement using stored ranks
__global__ void place_k(const int* __restrict__ src, const int* __restrict__ dst,
                        const int* __restrict__ rank, const int* __restrict__ row_start,
                        int* __restrict__ csr_dst) {
    int e = blockIdx.x * blockDim.x + threadIdx.x;
    if (e < EE) csr_dst[row_start[src[e]] + rank[e]] = dst[e];
}

// ---------------- h = l2norm(leakyrelu(x@W + b)) ----------------
// 4 nodes per wave: lane = (q=node slot)<<4 | (r=col quad). W staged in LDS.
// Writes f32 table (residual/initial h_dst) and bf16 table (edge gathers).

__device__ __forceinline__ unsigned short f2bf(float f) {
    unsigned u = __float_as_uint(f);
    return (unsigned short)((u + 0x7fffu + ((u >> 16) & 1u)) >> 16);  // RNE
}

__global__ __launch_bounds__(256) void gemm_norm_k(const float* __restrict__ x,
                                                   const float* __restrict__ w,
                                                   const float* __restrict__ bias,
                                                   float* __restrict__ hn,
                                                   unsigned short* __restrict__ hn16) {
    __shared__ float wl[INF_ * OUTF];     // 32 KB, [i][c]
    __shared__ float xl[4][4 * 132];      // 4 waves x 4 rows x (128 + 4 pad)
    for (int i = threadIdx.x; i < INF_ * OUTF; i += 256) wl[i] = w[i];

    int wv = threadIdx.x >> 6;
    int l  = threadIdx.x & 63;
    int q  = l >> 4;          // node slot within wave
    int r  = l & 15;          // col quad: cols 4r..4r+3
    float4 bv = ((const float4*)bias)[r];

    int n0 = (blockIdx.x * 4 + wv) * 4;   // 2500 blocks x 4 waves x 4 nodes = 40000
    {
        const float4* xs = (const float4*)(x + (size_t)n0 * INF_);
        float4 a = xs[l];
        float4 b = xs[l + 64];
        int ra = l >> 5, ca = (l & 31) * 4;
        int rb = (l + 64) >> 5, cb = ((l + 64) & 31) * 4;
        *(float4*)&xl[wv][ra * 132 + ca] = a;
        *(float4*)&xl[wv][rb * 132 + cb] = b;
    }
    __syncthreads();   // covers wl too

    float4 acc = bv;
    const float* xrow = &xl[wv][q * 132];
#pragma unroll 4
    for (int i = 0; i < INF_; ++i) {
        float xv = xrow[i];
        float4 w4 = ((const float4*)wl)[i * 16 + r];
        acc.x = fmaf(xv, w4.x, acc.x);
        acc.y = fmaf(xv, w4.y, acc.y);
        acc.z = fmaf(xv, w4.z, acc.z);
        acc.w = fmaf(xv, w4.w, acc.w);
    }
    acc.x = acc.x > 0.f ? acc.x : 0.01f * acc.x;
    acc.y = acc.y > 0.f ? acc.y : 0.01f * acc.y;
    acc.z = acc.z > 0.f ? acc.z : 0.01f * acc.z;
    acc.w = acc.w > 0.f ? acc.w : 0.01f * acc.w;
    float sq = acc.x*acc.x + acc.y*acc.y + acc.z*acc.z + acc.w*acc.w;
    sq += __shfl_xor(sq, 1);              // pair lanes within factor
    float inv = rsqrtf(sq);
    float4 o = make_float4(acc.x*inv, acc.y*inv, acc.z*inv, acc.w*inv);
    ((float4*)hn)[(size_t)(n0 + q) * 16 + r] = o;
    ushort4 o16;
    o16.x = f2bf(o.x); o16.y = f2bf(o.y); o16.z = f2bf(o.z); o16.w = f2bf(o.w);
    ((ushort4*)hn16)[(size_t)(n0 + q) * 16 + r] = o16;
}

// ---------------- fused 3-iteration attention ----------------
// h_dst[n]@t+1 depends only on h_dst[n]@t and the STATIC rows h_normed[dst(e)]
// of n's own edges -> no cross-node dependency -> all 3 iterations in one
// kernel, h_dst in registers, neighbor rows gathered ONCE into registers.
// lane = q<<3 | r: q = edge slot (0..7), r = factor (0..7, 8 bf16 = 1 uint4).
// Each lane caches edges q, q+8, q+16, q+24 (deg<=32 covers ~all nodes,
// Poisson(16); rare tail streamed from L2 each iteration).
// No max-subtraction: s = <u,v> in [-1,1] for unit vectors, exp always safe.

__global__ __launch_bounds__(256) void attn_fused_k(const uint4* __restrict__ hg,
                                                    const float* __restrict__ hnf,
                                                    float* __restrict__ out,
                                                    const int* __restrict__ row_start,
                                                    const int* __restrict__ csr_dst) {
    int wv = threadIdx.x >> 6;
    int l  = threadIdx.x & 63;
    int n  = blockIdx.x * 4 + wv;
    if (n >= NN) return;
    int q = l >> 3, r = l & 7;

    int beg = row_start[n], end = row_start[n + 1];
    int e0  = beg + q;

    bool v0 = e0      < end, v1 = e0 + 8  < end,
         v2 = e0 + 16 < end, v3 = e0 + 24 < end;

    // register cache: 4 independent gather chains issued up front
    uint4 fc0 = make_uint4(0,0,0,0), fc1 = fc0, fc2 = fc0, fc3 = fc0;
    if (v0) fc0 = hg[(size_t)csr_dst[e0     ] * 8 + r];
    if (v1) fc1 = hg[(size_t)csr_dst[e0 +  8] * 8 + r];
    if (v2) fc2 = hg[(size_t)csr_dst[e0 + 16] * 8 + r];
    if (v3) fc3 = hg[(size_t)csr_dst[e0 + 24] * 8 + r];

    const float4* hs4 = (const float4*)(hnf + (size_t)n * OUTF + r * 8);
    float4 hsa = hs4[0], hsb = hs4[1];   // residual (h_normed), f32
    float4 hda = hsa,   hdb = hsb;       // running h_dst, registers across iters

    for (int it = 0; it < 3; ++it) {
        float ssum = 0.f;
        float a0=0.f,a1=0.f,a2=0.f,a3=0.f,a4=0.f,a5=0.f,a6=0.f,a7=0.f;

        auto proc = [&](uint4 f, bool ok) {
            float f0 = __uint_as_float(f.x << 16), f1 = __uint_as_float(f.x & 0xffff0000u);
            float f2 = __uint_as_float(f.y << 16), f3 = __uint_as_float(f.y & 0xffff0000u);
            float f4 = __uint_as_float(f.z << 16), f5 = __uint_as_float(f.z & 0xffff0000u);
            float f6 = __uint_as_float(f.w << 16), f7 = __uint_as_float(f.w & 0xffff0000u);
            float p = f0*hda.x + f1*hda.y + f2*hda.z + f3*hda.w
                    + f4*hdb.x + f5*hdb.y + f6*hdb.z + f7*hdb.w;
            float ex = ok ? __expf(p) : 0.f;
            ssum += ex;
            a0 = fmaf(f0, ex, a0); a1 = fmaf(f1, ex, a1);
            a2 = fmaf(f2, ex, a2); a3 = fmaf(f3, ex, a3);
            a4 = fmaf(f4, ex, a4); a5 = fmaf(f5, ex, a5);
            a6 = fmaf(f6, ex, a6); a7 = fmaf(f7, ex, a7);
        };

        proc(fc0, v0); proc(fc1, v1); proc(fc2, v2); proc(fc3, v3);

        // rare tail: deg > 32, stream from L2
        for (int e = beg + 32 + q; e < end; e += 8) {
            int dv = csr_dst[e];
            proc(hg[(size_t)dv * 8 + r], true);
        }

        // combine the 8 disjoint edge-slot partials across q
#pragma unroll
        for (int m = 8; m < 64; m <<= 1) {
            ssum += __shfl_xor(ssum, m);
            a0 += __shfl_xor(a0, m); a1 += __shfl_xor(a1, m);
            a2 += __shfl_xor(a2, m); a3 += __shfl_xor(a3, m);
            a4 += __shfl_xor(a4, m); a5 += __shfl_xor(a5, m);
            a6 += __shfl_xor(a6, m); a7 += __shfl_xor(a7, m);
        }

        float rs = (ssum > 0.f) ? 1.f / ssum : 0.f;  // empty segment -> residual only
        float t0 = fmaf(a0, rs, hsa.x), t1 = fmaf(a1, rs, hsa.y);
        float t2 = fmaf(a2, rs, hsa.z), t3 = fmaf(a3, rs, hsa.w);
        float t4 = fmaf(a4, rs, hsb.x), t5 = fmaf(a5, rs, hsb.y);
        float t6 = fmaf(a6, rs, hsb.z), t7 = fmaf(a7, rs, hsb.w);
        float sq = t0*t0+t1*t1+t2*t2+t3*t3+t4*t4+t5*t5+t6*t6+t7*t7;
        float inv = rsqrtf(sq);                      // per-factor l2 norm (in-lane)
        hda = make_float4(t0*inv, t1*inv, t2*inv, t3*inv);
        hdb = make_float4(t4*inv, t5*inv, t6*inv, t7*inv);
    }

    if (q == 0) {
        float4* o4 = (float4*)(out + (size_t)n * OUTF + r * 8);
        o4[0] = hda;
        o4[1] = hdb;
    }
}

// ---------------- launch ----------------

extern "C" void kernel_launch(void* const* d_in, const int* in_sizes, int n_in,
                              void* d_out, int out_size, void* d_ws, size_t ws_size,
                              hipStream_t stream) {
    const float* x    = (const float*)d_in[0];
    const float* w    = (const float*)d_in[1];
    const float* bias = (const float*)d_in[2];
    const int*   ei   = (const int*)d_in[3];
    const int*   src  = ei;        // edge_index[0] : softmax segment node
    const int*   dst  = ei + EE;   // edge_index[1] : gathered neighbor
    float* out = (float*)d_out;

    char* ws = (char*)d_ws;
    size_t off = 0;
    float*          hn   = (float*)(ws + off);          off += (size_t)NN * OUTF * sizeof(float);  // 10.24 MB
    unsigned short* hn16 = (unsigned short*)(ws + off); off += (size_t)NN * OUTF * sizeof(short);  // 5.12 MB
    int* counts    = (int*)(ws + off); off += (size_t)NN * sizeof(int);
    int* excl      = (int*)(ws + off); off += (size_t)NN * sizeof(int);
    int* bsum      = (int*)(ws + off); off += 256 * sizeof(int);
    int* row_start = (int*)(ws + off); off += (size_t)(NN + 1) * sizeof(int);
    int* rank      = (int*)(ws + off); off += (size_t)EE * sizeof(int);
    int* csr_dst   = (int*)(ws + off); off += (size_t)EE * sizeof(int);
    (void)ws_size; (void)in_sizes; (void)n_in; (void)out_size;

    const int nscan = (NN + 255) / 256;   // 157

    zero_k <<<nscan, 256, 0, stream>>>(counts);
    hist_k <<<(EE/4 + 255) / 256, 256, 0, stream>>>((const int4*)src, counts, (int4*)rank);
    scan1_k<<<nscan, 256, 0, stream>>>(counts, excl, bsum);
    scan2_k<<<1, 256, 0, stream>>>(bsum, nscan);
    scan3_k<<<nscan, 256, 0, stream>>>(excl, bsum, row_start);
    place_k<<<(EE + 255) / 256, 256, 0, stream>>>(src, dst, rank, row_start, csr_dst);

    gemm_norm_k<<<NN / 16, 256, 0, stream>>>(x, w, bias, hn, hn16);

    attn_fused_k<<<(NN + 3) / 4, 256, 0, stream>>>((const uint4*)hn16, hn, out,
                                                   row_start, csr_dst);
}

// Round 5
// 112.594 us; speedup vs baseline: 2.8347x; 1.0043x over previous
//
#include <hip/hip_runtime.h>
#include <math.h>

#define NN   40000     // nodes
#define EE   640000    // edges
#define INF_ 128       // in feats
#define OUTF 64        // out feats (K=8 factors x d=8)

typedef float f2 __attribute__((ext_vector_type(2)));

__device__ __forceinline__ f2 pkfma(f2 a, f2 b, f2 c) {
    return __builtin_elementwise_fma(a, b, c);   // v_pk_fma_f32
}
__device__ __forceinline__ f2 shf2(f2 a, int m) {
    f2 b; b.x = __shfl_xor(a.x, m); b.y = __shfl_xor(a.y, m); return b;
}
__device__ __forceinline__ f2 bfpair(unsigned u) {
    f2 c;
    c.x = __uint_as_float(u << 16);
    c.y = __uint_as_float(u & 0xffff0000u);
    return c;
}

// ---------------- CSR construction ----------------

__global__ void zero_k(int* __restrict__ c) {
    int i = blockIdx.x * 256 + threadIdx.x;
    if (i < NN) c[i] = 0;
}

// histogram; atomicAdd return value = within-segment rank
__global__ void hist_k(const int4* __restrict__ src4, int* __restrict__ counts,
                       int4* __restrict__ rank4) {
    int t = blockIdx.x * blockDim.x + threadIdx.x;
    if (t < EE / 4) {
        int4 s = src4[t];
        int4 r;
        r.x = atomicAdd(&counts[s.x], 1);
        r.y = atomicAdd(&counts[s.y], 1);
        r.z = atomicAdd(&counts[s.z], 1);
        r.w = atomicAdd(&counts[s.w], 1);
        rank4[t] = r;
    }
}

__global__ void scan1_k(const int* __restrict__ counts, int* __restrict__ excl,
                        int* __restrict__ bsum) {
    __shared__ int tmp[256];
    int i = blockIdx.x * 256 + threadIdx.x;
    int v = (i < NN) ? counts[i] : 0;
    tmp[threadIdx.x] = v;
    __syncthreads();
    for (int off = 1; off < 256; off <<= 1) {
        int t = (threadIdx.x >= off) ? tmp[threadIdx.x - off] : 0;
        __syncthreads();
        tmp[threadIdx.x] += t;
        __syncthreads();
    }
    if (i < NN) excl[i] = tmp[threadIdx.x] - v;          // exclusive within block
    if (threadIdx.x == 255) bsum[blockIdx.x] = tmp[255]; // block total
}

__global__ void scan2_k(int* __restrict__ bsum, int nb) {
    __shared__ int tmp[256];
    int v = (threadIdx.x < nb) ? bsum[threadIdx.x] : 0;
    tmp[threadIdx.x] = v;
    __syncthreads();
    for (int off = 1; off < 256; off <<= 1) {
        int t = (threadIdx.x >= off) ? tmp[threadIdx.x - off] : 0;
        __syncthreads();
        tmp[threadIdx.x] += t;
        __syncthreads();
    }
    if (threadIdx.x < nb) bsum[threadIdx.x] = tmp[threadIdx.x] - v; // exclusive in place
}

// atomic-free placement; row_start computed inline (excl + spine)
__global__ void place_k(const int4* __restrict__ src4, const int4* __restrict__ dst4,
                        const int4* __restrict__ rank4, const int* __restrict__ excl,
                        const int* __restrict__ bsum, int* __restrict__ csr_dst) {
    int t = blockIdx.x * blockDim.x + threadIdx.x;
    if (t < EE / 4) {
        int4 s = src4[t];
        int4 d = dst4[t];
        int4 r = rank4[t];
        csr_dst[excl[s.x] + bsum[s.x >> 8] + r.x] = d.x;
        csr_dst[excl[s.y] + bsum[s.y >> 8] + r.y] = d.y;
        csr_dst[excl[s.z] + bsum[s.z >> 8] + r.z] = d.z;
        csr_dst[excl[s.w] + bsum[s.w >> 8] + r.w] = d.w;
    }
}

// ---------------- h = l2norm(leakyrelu(x@W + b)) ----------------
// 16 nodes per wave (64/block, 625 blocks): W staged once in LDS, x rows
// double-buffered per wave. lane = (q=node slot)<<4 | (rr=col quad).

__device__ __forceinline__ unsigned short f2bf(float f) {
    unsigned u = __float_as_uint(f);
    return (unsigned short)((u + 0x7fffu + ((u >> 16) & 1u)) >> 16);  // RNE
}

__global__ __launch_bounds__(256) void gemm_norm_k(const float* __restrict__ x,
                                                   const float* __restrict__ w,
                                                   const float* __restrict__ bias,
                                                   float* __restrict__ hn,
                                                   unsigned short* __restrict__ hn16) {
    __shared__ float wl[INF_ * OUTF];       // 32 KB, [i][c]
    __shared__ float xl[4][2][4 * 132];     // per-wave double-buffered x rows
    for (int i = threadIdx.x; i < INF_ * OUTF; i += 256) wl[i] = w[i];

    int wv = threadIdx.x >> 6;
    int l  = threadIdx.x & 63;
    int q  = l >> 4;           // node slot within group
    int rr = l & 15;           // col quad: cols 4rr..4rr+3
    float4 bv = ((const float4*)bias)[rr];
    int ra = l >> 5,        ca = (l & 31) * 4;
    int rb = (l + 64) >> 5, cb = ((l + 64) & 31) * 4;

    int nb = (blockIdx.x * 4 + wv) * 16;    // 625 blocks x 4 waves x 16 nodes

    // prefill buffer 0
    {
        const float4* xs = (const float4*)(x + (size_t)nb * INF_);
        *(float4*)&xl[wv][0][ra * 132 + ca] = xs[l];
        *(float4*)&xl[wv][0][rb * 132 + cb] = xs[l + 64];
    }
    __syncthreads();   // covers wl (only barrier needed)

#pragma unroll
    for (int g = 0; g < 4; ++g) {
        int n0 = nb + g * 4;
        if (g < 3) {   // stage next group into other buffer (wave-local)
            const float4* xs = (const float4*)(x + (size_t)(n0 + 4) * INF_);
            *(float4*)&xl[wv][(g + 1) & 1][ra * 132 + ca] = xs[l];
            *(float4*)&xl[wv][(g + 1) & 1][rb * 132 + cb] = xs[l + 64];
        }
        float4 acc = bv;
        const float* xrow = &xl[wv][g & 1][q * 132];
#pragma unroll 4
        for (int i = 0; i < INF_; ++i) {
            float xv = xrow[i];
            float4 w4 = ((const float4*)wl)[i * 16 + rr];
            acc.x = fmaf(xv, w4.x, acc.x);
            acc.y = fmaf(xv, w4.y, acc.y);
            acc.z = fmaf(xv, w4.z, acc.z);
            acc.w = fmaf(xv, w4.w, acc.w);
        }
        acc.x = acc.x > 0.f ? acc.x : 0.01f * acc.x;
        acc.y = acc.y > 0.f ? acc.y : 0.01f * acc.y;
        acc.z = acc.z > 0.f ? acc.z : 0.01f * acc.z;
        acc.w = acc.w > 0.f ? acc.w : 0.01f * acc.w;
        float sq = acc.x*acc.x + acc.y*acc.y + acc.z*acc.z + acc.w*acc.w;
        sq += __shfl_xor(sq, 1);            // pair lanes within factor
        float inv = rsqrtf(sq);
        float4 o = make_float4(acc.x*inv, acc.y*inv, acc.z*inv, acc.w*inv);
        ((float4*)hn)[(size_t)(n0 + q) * 16 + rr] = o;
        ushort4 o16;
        o16.x = f2bf(o.x); o16.y = f2bf(o.y); o16.z = f2bf(o.z); o16.w = f2bf(o.w);
        ((ushort4*)hn16)[(size_t)(n0 + q) * 16 + rr] = o16;
    }
}

// ---------------- fused 3-iteration attention ----------------
// One wave per node. lane = q<<3 | r (q = edge slot 0..7, r = factor 0..7).
// Edges gathered ONCE (deg<=32 register-cached, pre-unpacked to f32 pairs);
// all 3 iterations run on registers. Packed f32 math (v_pk_fma_f32) halves
// FMA issue slots. No max-subtraction: s = <u,v> in [-1,1] for unit vectors.

__global__ __launch_bounds__(256) void attn_fused_k(const uint4* __restrict__ hg,
                                                    const float* __restrict__ hnf,
                                                    float* __restrict__ out,
                                                    const int* __restrict__ excl,
                                                    const int* __restrict__ bsum,
                                                    const int* __restrict__ csr_dst) {
    int wv = threadIdx.x >> 6;
    int l  = threadIdx.x & 63;
    int n  = blockIdx.x * 4 + wv;
    if (n >= NN) return;
    int q = l >> 3, r = l & 7;

    int beg = excl[n] + bsum[n >> 8];
    int end = (n + 1 < NN) ? (excl[n + 1] + bsum[(n + 1) >> 8]) : EE;

    // one coalesced index load for the whole wave, then broadcast
    int el  = beg + l;
    int idx = (el < end) ? csr_dst[el] : -1;
    int i0 = __shfl(idx, q);
    int i1 = __shfl(idx, q + 8);
    int i2 = __shfl(idx, q + 16);
    int i3 = __shfl(idx, q + 24);
    bool v0 = i0 >= 0, v1 = i1 >= 0, v2 = i2 >= 0, v3 = i3 >= 0;

    uint4 g0 = hg[(size_t)(v0 ? i0 : 0) * 8 + r];
    uint4 g1 = hg[(size_t)(v1 ? i1 : 0) * 8 + r];
    uint4 g2 = hg[(size_t)(v2 ? i2 : 0) * 8 + r];
    uint4 g3 = hg[(size_t)(v3 ? i3 : 0) * 8 + r];

    // pre-unpack cached edges to f32 pairs (once, reused by all 3 iterations)
    f2 e0c0 = bfpair(g0.x), e0c1 = bfpair(g0.y), e0c2 = bfpair(g0.z), e0c3 = bfpair(g0.w);
    f2 e1c0 = bfpair(g1.x), e1c1 = bfpair(g1.y), e1c2 = bfpair(g1.z), e1c3 = bfpair(g1.w);
    f2 e2c0 = bfpair(g2.x), e2c1 = bfpair(g2.y), e2c2 = bfpair(g2.z), e2c3 = bfpair(g2.w);
    f2 e3c0 = bfpair(g3.x), e3c1 = bfpair(g3.y), e3c2 = bfpair(g3.z), e3c3 = bfpair(g3.w);

    const float4* hs4 = (const float4*)(hnf + (size_t)n * OUTF + r * 8);
    float4 ha = hs4[0], hb = hs4[1];
    f2 hs01 = {ha.x, ha.y}, hs23 = {ha.z, ha.w}, hs45 = {hb.x, hb.y}, hs67 = {hb.z, hb.w};
    f2 hd01 = hs01, hd23 = hs23, hd45 = hs45, hd67 = hs67;  // running h_dst

    for (int it = 0; it < 3; ++it) {
        float ssum = 0.f;
        f2 A0 = {0.f, 0.f}, A1 = A0, A2 = A0, A3 = A0;

        auto proc = [&](f2 c0, f2 c1, f2 c2, f2 c3, bool ok) {
            f2 d = c0 * hd01;                 // v_pk_mul_f32
            d = pkfma(c1, hd23, d);
            d = pkfma(c2, hd45, d);
            d = pkfma(c3, hd67, d);
            float p  = d.x + d.y;             // full 8-dot, in-lane
            float ex = ok ? __expf(p) : 0.f;
            ssum += ex;
            f2 exv = {ex, ex};
            A0 = pkfma(c0, exv, A0);
            A1 = pkfma(c1, exv, A1);
            A2 = pkfma(c2, exv, A2);
            A3 = pkfma(c3, exv, A3);
        };

        proc(e0c0, e0c1, e0c2, e0c3, v0);
        proc(e1c0, e1c1, e1c2, e1c3, v1);
        proc(e2c0, e2c1, e2c2, e2c3, v2);
        proc(e3c0, e3c1, e3c2, e3c3, v3);

        // rare tail: deg > 32, stream from L2
        for (int e = beg + 32 + q; e < end; e += 8) {
            uint4 f = hg[(size_t)csr_dst[e] * 8 + r];
            proc(bfpair(f.x), bfpair(f.y), bfpair(f.z), bfpair(f.w), true);
        }

        // combine the 8 disjoint edge-slot partials across q
#pragma unroll
        for (int m = 8; m < 64; m <<= 1) {
            ssum += __shfl_xor(ssum, m);
            A0 += shf2(A0, m);
            A1 += shf2(A1, m);
            A2 += shf2(A2, m);
            A3 += shf2(A3, m);
        }

        float rs = (ssum > 0.f) ? 1.f / ssum : 0.f;   // empty segment -> residual only
        f2 rsv = {rs, rs};
        f2 t01 = pkfma(A0, rsv, hs01);
        f2 t23 = pkfma(A1, rsv, hs23);
        f2 t45 = pkfma(A2, rsv, hs45);
        f2 t67 = pkfma(A3, rsv, hs67);
        f2 d = t01 * t01;
        d = pkfma(t23, t23, d);
        d = pkfma(t45, t45, d);
        d = pkfma(t67, t67, d);
        float inv = rsqrtf(d.x + d.y);                // per-factor l2 norm (in-lane)
        f2 iv = {inv, inv};
        hd01 = t01 * iv; hd23 = t23 * iv; hd45 = t45 * iv; hd67 = t67 * iv;
    }

    if (q == 0) {
        float4* o4 = (float4*)(out + (size_t)n * OUTF + r * 8);
        o4[0] = make_float4(hd01.x, hd01.y, hd23.x, hd23.y);
        o4[1] = make_float4(hd45.x, hd45.y, hd67.x, hd67.y);
    }
}

// ---------------- launch ----------------

extern "C" void kernel_launch(void* const* d_in, const int* in_sizes, int n_in,
                              void* d_out, int out_size, void* d_ws, size_t ws_size,
                              hipStream_t stream) {
    const float* x    = (const float*)d_in[0];
    const float* w    = (const float*)d_in[1];
    const float* bias = (const float*)d_in[2];
    const int*   ei   = (const int*)d_in[3];
    const int*   src  = ei;        // edge_index[0] : softmax segment node
    const int*   dst  = ei + EE;   // edge_index[1] : gathered neighbor
    float* out = (float*)d_out;

    char* ws = (char*)d_ws;
    size_t off = 0;
    float*          hn   = (float*)(ws + off);          off += (size_t)NN * OUTF * sizeof(float);  // 10.24 MB
    unsigned short* hn16 = (unsigned short*)(ws + off); off += (size_t)NN * OUTF * sizeof(short);  // 5.12 MB
    int* counts  = (int*)(ws + off); off += (size_t)NN * sizeof(int);
    int* excl    = (int*)(ws + off); off += (size_t)NN * sizeof(int);
    int* bsum    = (int*)(ws + off); off += 256 * sizeof(int);
    int* rank    = (int*)(ws + off); off += (size_t)EE * sizeof(int);
    int* csr_dst = (int*)(ws + off); off += (size_t)EE * sizeof(int);
    (void)ws_size; (void)in_sizes; (void)n_in; (void)out_size;

    const int nscan = (NN + 255) / 256;   // 157

    zero_k <<<nscan, 256, 0, stream>>>(counts);
    hist_k <<<(EE/4 + 255) / 256, 256, 0, stream>>>((const int4*)src, counts, (int4*)rank);
    scan1_k<<<nscan, 256, 0, stream>>>(counts, excl, bsum);
    scan2_k<<<1, 256, 0, stream>>>(bsum, nscan);
    place_k<<<(EE/4 + 255) / 256, 256, 0, stream>>>((const int4*)src, (const int4*)dst,
                                                    (const int4*)rank, excl, bsum, csr_dst);

    gemm_norm_k<<<NN / 64, 256, 0, stream>>>(x, w, bias, hn, hn16);   // 625 blocks

    attn_fused_k<<<(NN + 3) / 4, 256, 0, stream>>>((const uint4*)hn16, hn, out,
                                                   excl, bsum, csr_dst);
}